// Round 1
// 425.642 us; speedup vs baseline: 1.0507x; 1.0507x over previous
//
#include <hip/hip_runtime.h>
#include <math.h>

#define N_ 64
#define C_ 1024
#define HW_ 1024
#define SIZE_ 32
#define CSPLIT 32
#define CCHUNK (C_ / CSPLIT)   // 32 channels per block

typedef float f4 __attribute__((ext_vector_type(4)));

// ---------------------------------------------------------------------------
// K1: partial channel sums. grid = N_*CSPLIT = 2048 blocks, 256 threads
// (8 blocks/CU -> 32 waves/CU). Thread t owns float4 column t; sums CCHUNK
// channels in fixed order (deterministic for stable argmax).
// x is streamed once with ZERO reuse -> nontemporal loads (no L1/L2/L3
// allocation, avoids thrashing the 256MB L3 with a 268MB stream).
__global__ __launch_bounds__(256, 8)
void k_partial(const float* __restrict__ x, float* __restrict__ partial) {
    const int b = blockIdx.x;
    const int n = b >> 5;
    const int s = b & 31;
    const int t = threadIdx.x;

    const f4* p = (const f4*)(x + ((size_t)(n * C_ + s * CCHUNK)) * HW_) + t;
    f4 acc = {0.f, 0.f, 0.f, 0.f};
    #pragma unroll 8
    for (int c = 0; c < CCHUNK; ++c) {
        f4 v = __builtin_nontemporal_load(p + (size_t)c * (HW_ / 4));
        acc += v;
    }
    // partial IS reused (k_reduce reads it next) -> normal cached store
    ((f4*)(partial + (size_t)b * HW_))[t] = acc;
}

// ---------------------------------------------------------------------------
// K2: per-sample reduction. grid = N_ blocks of 256 threads.
// fold partials -> threshold -> reduced_x (ws) -> first-index argmax ->
// anchor/index/polar outputs.
__global__ __launch_bounds__(256, 4)
void k_reduce(const float* __restrict__ partial, float* __restrict__ reduced,
              float* __restrict__ out0 /*[N,HW,2]*/,
              float* __restrict__ out1 /*[N,2]*/,
              float* __restrict__ out3 /*[N]*/) {
    const int n = blockIdx.x;
    const int t = threadIdx.x;
    const int wave = t >> 6, lane = t & 63;

    __shared__ float s_sum[4];
    __shared__ float s_val[4];
    __shared__ int   s_idx[4];
    __shared__ float s_thr;
    __shared__ int   s_best;

    float4 m = make_float4(0.f, 0.f, 0.f, 0.f);
    #pragma unroll 8
    for (int s = 0; s < CSPLIT; ++s) {
        float4 v = ((const float4*)(partial + (size_t)(n * CSPLIT + s) * HW_))[t];
        m.x += v.x; m.y += v.y; m.z += v.z; m.w += v.w;
    }

    // threshold = mean over HW of mask
    float lsum = m.x + m.y + m.z + m.w;
    #pragma unroll
    for (int off = 32; off >= 1; off >>= 1) lsum += __shfl_down(lsum, off, 64);
    if (lane == 0) s_sum[wave] = lsum;
    __syncthreads();
    if (t == 0) s_thr = (s_sum[0] + s_sum[1] + s_sum[2] + s_sum[3]) * (1.0f / HW_);
    __syncthreads();
    const float thr = s_thr;

    // reduced_x = binary * mask / C
    float4 r;
    r.x = (m.x > thr) ? m.x * (1.0f / C_) : 0.0f;
    r.y = (m.y > thr) ? m.y * (1.0f / C_) : 0.0f;
    r.z = (m.z > thr) ? m.z * (1.0f / C_) : 0.0f;
    r.w = (m.w > thr) ? m.w * (1.0f / C_) : 0.0f;
    ((float4*)(reduced + (size_t)n * HW_))[t] = r;

    // first-index argmax over reduced_x
    float bv = r.x; int bi = 4 * t;
    if (r.y > bv) { bv = r.y; bi = 4 * t + 1; }
    if (r.z > bv) { bv = r.z; bi = 4 * t + 2; }
    if (r.w > bv) { bv = r.w; bi = 4 * t + 3; }
    #pragma unroll
    for (int off = 32; off >= 1; off >>= 1) {
        float ov = __shfl_down(bv, off, 64);
        int   oi = __shfl_down(bi, off, 64);
        if (ov > bv || (ov == bv && oi < bi)) { bv = ov; bi = oi; }
    }
    if (lane == 0) { s_val[wave] = bv; s_idx[wave] = bi; }
    __syncthreads();
    if (t == 0) {
        float v0 = s_val[0]; int i0 = s_idx[0];
        #pragma unroll
        for (int w2 = 1; w2 < 4; ++w2) {
            if (s_val[w2] > v0 || (s_val[w2] == v0 && s_idx[w2] < i0)) {
                v0 = s_val[w2]; i0 = s_idx[w2];
            }
        }
        s_best = i0;
        out1[n * 2 + 0] = (float)(i0 >> 5);
        out1[n * 2 + 1] = (float)(i0 & 31);
        out3[n] = (float)i0;
    }
    __syncthreads();
    const int   best = s_best;
    const float ai = (float)(best >> 5);
    const float aj = (float)(best & 31);

    float res[8];
    float binv[4] = { (m.x > thr) ? 1.f : 0.f, (m.y > thr) ? 1.f : 0.f,
                      (m.z > thr) ? 1.f : 0.f, (m.w > thr) ? 1.f : 0.f };
    #pragma unroll
    for (int k = 0; k < 4; ++k) {
        int hw = 4 * t + k;
        float dy = ((float)(hw >> 5) - ai) * (1.0f / SIZE_);
        float dx = ((float)(hw & 31) - aj) * (1.0f / SIZE_);
        float dist = sqrtf(dy * dy + dx * dx);
        float ang = atan2f(dx, dy) * 0.15915494309189535f + 0.5f;
        res[2 * k]     = dist * binv[k];
        res[2 * k + 1] = ang * binv[k];
    }
    float4* o = (float4*)(out0 + ((size_t)n * HW_ + 4 * t) * 2);
    o[0] = make_float4(res[0], res[1], res[2], res[3]);
    o[1] = make_float4(res[4], res[5], res[6], res[7]);
}

// ---------------------------------------------------------------------------
// K3: position_weight[n,i,j] = reduced[n,i] * reduced[n,j].
// grid = N_ * (HW_/8) = 8192 blocks, 8 rows per block, float4 stores
// (1 KB per wave-instruction, fully coalesced). `reduced` is L2-resident.
// out2 is a 268MB write-once stream -> nontemporal stores (no write-allocate
// pollution of L2/L3).
__global__ __launch_bounds__(256, 8)
void k_outer(const float* __restrict__ reduced, float* __restrict__ out2) {
    const int b = blockIdx.x;
    const int n = b >> 7;                 // 128 blocks per n
    const int ibase = (b & 127) * 8;
    const int t = threadIdx.x;

    const float* rrow = reduced + (size_t)n * HW_;
    f4 rj = ((const f4*)rrow)[t];
    f4* obase = (f4*)(out2 + (size_t)(n * HW_ + ibase) * HW_) + t;
    #pragma unroll
    for (int r = 0; r < 8; ++r) {
        float ri = rrow[ibase + r];
        __builtin_nontemporal_store(ri * rj, obase + (size_t)r * (HW_ / 4));
    }
}

// ---------------------------------------------------------------------------
extern "C" void kernel_launch(void* const* d_in, const int* in_sizes, int n_in,
                              void* d_out, int out_size, void* d_ws, size_t ws_size,
                              hipStream_t stream) {
    const float* x = (const float*)d_in[0];
    float* out = (float*)d_out;
    float* out0 = out;                       // [64,1024,2]
    float* out1 = out + 131072;              // [64,2]
    float* out2 = out + 131200;              // [64,1024,1024]
    float* out3 = out + 131200 + 67108864;   // [64]

    float* partial = (float*)d_ws;                        // [N, CSPLIT, HW] = 8 MB
    float* reduced = partial + (size_t)N_ * CSPLIT * HW_; // [N, HW]

    k_partial<<<N_ * CSPLIT, 256, 0, stream>>>(x, partial);
    k_reduce<<<N_, 256, 0, stream>>>(partial, reduced, out0, out1, out3);
    k_outer<<<N_ * (HW_ / 8), 256, 0, stream>>>(reduced, out2);
}